// Round 9
// baseline (473.235 us; speedup 1.0000x reference)
//
#include <hip/hip_runtime.h>
#include <hip/hip_bf16.h>
#include <cstdint>
#include <cstddef>

#define NB 2
#define NSEQ 2048
#define NHEADS 16
#define HD 64
#define DMODEL 1024
#define SCALEF 0.125f

typedef __attribute__((ext_vector_type(4))) float f32x4;
typedef __attribute__((ext_vector_type(8))) short s16x8;
typedef __attribute__((ext_vector_type(4))) short s16x4;

__device__ __forceinline__ unsigned short f2bf(float f) {
  union { float f; unsigned u; } v; v.f = f;
  unsigned u = v.u;
  return (unsigned short)((u + 0x7fffu + ((u >> 16) & 1u)) >> 16);
}
__device__ __forceinline__ float bf2f(unsigned short s) {
  union { unsigned u; float f; } v; v.u = ((unsigned)s) << 16;
  return v.f;
}

// ---------- fp32 -> bf16 straight convert (float4 vectorized) ----------
__global__ void k_convert(const float* __restrict__ in, unsigned short* __restrict__ out, int n4) {
  int i = blockIdx.x * blockDim.x + threadIdx.x;
  if (i >= n4) return;
  float4 v = ((const float4*)in)[i];
  ushort4 o;
  o.x = f2bf(v.x); o.y = f2bf(v.y); o.z = f2bf(v.z); o.w = f2bf(v.w);
  ((ushort4*)out)[i] = o;
}

// ---------- w [K][N] fp32 -> wt [N][K] bf16 (LDS-tiled transpose) ----------
__global__ void k_transpose(const float* __restrict__ w, unsigned short* __restrict__ wt, int K, int N) {
  __shared__ float t[64][65];
  int n0 = blockIdx.x * 64, k0 = blockIdx.y * 64;
  int c = threadIdx.x & 63, rb = threadIdx.x >> 6;
#pragma unroll
  for (int rr = 0; rr < 16; rr++) {
    int k = rb * 16 + rr;
    t[c][k] = w[(size_t)(k0 + k) * N + n0 + c];
  }
  __syncthreads();
#pragma unroll
  for (int rr = 0; rr < 16; rr++) {
    int n = rb * 16 + rr;
    wt[(size_t)(n0 + n) * K + k0 + c] = f2bf(t[n][c]);
  }
}

// ---------- bf16 MFMA GEMM: C[M][N] = A[M][K] @ Bt[N][K]^T (+bias) ----------
#define GLD16(gp, lp) __builtin_amdgcn_global_load_lds( \
    (const __attribute__((address_space(1))) unsigned int*)(gp), \
    (__attribute__((address_space(3))) unsigned int*)(lp), 16, 0, 0)

__global__ __launch_bounds__(256) void k_gemm(const unsigned short* __restrict__ A,
                                              const unsigned short* __restrict__ Bt,
                                              float* __restrict__ C,
                                              const float* __restrict__ bias,
                                              int M, int N, int K) {
  __shared__ unsigned short As[128 * 32];
  __shared__ unsigned short Bs[128 * 32];
  const int tid = threadIdx.x;
  const int lane = tid & 63, wid = tid >> 6;
  const int m0 = blockIdx.y * 128, n0 = blockIdx.x * 128;
  const int wr = wid >> 1, wc = wid & 1;
  const int lr = lane >> 2, l4 = lane & 3;
  const int lc = lane & 15, lg = lane >> 4;

  const unsigned short* pa0 = A + (size_t)(m0 + wid * 32 + lr) * K + l4 * 8;
  const unsigned short* pa1 = pa0 + (size_t)16 * K;
  const unsigned short* pb0 = Bt + (size_t)(n0 + wid * 32 + lr) * K + l4 * 8;
  const unsigned short* pb1 = pb0 + (size_t)16 * K;

  f32x4 acc[4][4] = {};

  for (int kt = 0; kt < K; kt += 32) {
    GLD16(pa0 + kt, &As[wid * 1024]);
    GLD16(pa1 + kt, &As[wid * 1024 + 512]);
    GLD16(pb0 + kt, &Bs[wid * 1024]);
    GLD16(pb1 + kt, &Bs[wid * 1024 + 512]);
    __syncthreads();
    s16x8 af[4], bfr[4];
#pragma unroll
    for (int m = 0; m < 4; m++)
      af[m] = *(const s16x8*)&As[(wr * 64 + m * 16 + lc) * 32 + lg * 8];
#pragma unroll
    for (int n = 0; n < 4; n++)
      bfr[n] = *(const s16x8*)&Bs[(wc * 64 + n * 16 + lc) * 32 + lg * 8];
    __builtin_amdgcn_s_setprio(1);
#pragma unroll
    for (int m = 0; m < 4; m++)
#pragma unroll
      for (int n = 0; n < 4; n++)
        acc[m][n] = __builtin_amdgcn_mfma_f32_16x16x32_bf16(af[m], bfr[n], acc[m][n], 0, 0, 0);
    __builtin_amdgcn_s_setprio(0);
    __syncthreads();
  }

  float bv[4] = {0.f, 0.f, 0.f, 0.f};
  if (bias) {
#pragma unroll
    for (int n = 0; n < 4; n++) bv[n] = bias[n0 + wc * 64 + n * 16 + lc];
  }
#pragma unroll
  for (int m = 0; m < 4; m++) {
#pragma unroll
    for (int n = 0; n < 4; n++) {
      int col = n0 + wc * 64 + n * 16 + lc;
#pragma unroll
      for (int r = 0; r < 4; r++) {
        int row = m0 + wr * 64 + m * 16 + lg * 4 + r;
        C[(size_t)row * N + col] = acc[m][n][r] + bv[n];
      }
    }
  }
}

// ---------- RoPE + head-split relayout: [B][N][H*64] f32 -> [B][H][N][64] bf16 ----------
__global__ void k_rope(const float* __restrict__ src, int row_stride,
                       const float* __restrict__ sinp, const float* __restrict__ cosp,
                       unsigned short* __restrict__ dst) {
  int tid = blockIdx.x * 256 + threadIdx.x;
  int p = tid & 31;
  int h = (tid >> 5) & 15;
  int i = (tid >> 9) & 2047;
  int b = tid >> 20;
  int d = p * 2;
  float2 x = *(const float2*)(src + (size_t)(b * NSEQ + i) * row_stride + h * HD + d);
  float o0, o1;
  if (p < 16) {
    size_t sc = (size_t)(b * NSEQ + i) * 32 + d;
    float2 cc = *(const float2*)(cosp + sc);
    float2 ss = *(const float2*)(sinp + sc);
    o0 = x.x * cc.x - x.y * ss.x;
    o1 = x.y * cc.y + x.x * ss.y;
  } else { o0 = x.x; o1 = x.y; }
  size_t off = ((size_t)(b * NHEADS + h) * NSEQ + i) * HD + d;
  unsigned pack = (unsigned)f2bf(o0) | ((unsigned)f2bf(o1) << 16);
  *(unsigned*)(dst + off) = pack;
}

// ---------- v relayout+transpose: kv[B][N][2048](cols 1024..) -> vt [B][H][64][N] bf16 ----------
__global__ void k_vtrans(const float* __restrict__ kv, unsigned short* __restrict__ vt) {
  __shared__ float t[64][65];
  int i0 = blockIdx.x * 64;
  int h = blockIdx.y, b = blockIdx.z;
  int c = threadIdx.x & 63, rb = threadIdx.x >> 6;
#pragma unroll
  for (int rr = 0; rr < 16; rr++) {
    int il = rb * 16 + rr;
    t[il][c] = kv[(size_t)(b * NSEQ + i0 + il) * 2048 + 1024 + h * HD + c];
  }
  __syncthreads();
#pragma unroll
  for (int rr = 0; rr < 16; rr++) {
    int dd = rb * 16 + rr;
    vt[((size_t)(b * NHEADS + h) * HD + dd) * NSEQ + i0 + c] = f2bf(t[c][dd]);
  }
}

// ---------- fused attention v8: swapped QK^T, register-resident e, no Sbf ----------
// mfma(K,Q) puts attn ROWS lane-local: D col=lane&15=q-row, row=lg*4+r=j.
// e lives in 32 VGPR bf16; row-sum = 2 shuffles; attn store streams from regs
// interleaved into the PV loop (overlaps the 537MB write with MFMA+V loads).
// PV uses v_mfma_f32_16x16x16_bf16 (K=16): its B-frag layout (k=lg*4+m,
// col=lane&15) IS the QK^T output layout -> zero cross-lane redistribution.
#define QBLK 32
__global__ __launch_bounds__(1024, 4) void k_attn(const unsigned short* __restrict__ qh,
                                                  const unsigned short* __restrict__ kh,
                                                  const unsigned short* __restrict__ vt,
                                                  float* __restrict__ attn_g,
                                                  unsigned short* __restrict__ ctx) {
  __shared__ float part[8][32][64];   // 65,536 B
  __shared__ float wred[16][32];
  __shared__ float invr[32];

  const int tid = threadIdx.x;
  const int lane = tid & 63, wid = tid >> 6;     // wid 0..15
  const int i0 = blockIdx.x * QBLK;
  const int h = blockIdx.y, b = blockIdx.z;
  const int lc = lane & 15, lg = lane >> 4;
  const int wcb = wid * 128;                     // wave's 128-col j-slice

  const unsigned short* qb = qh + ((size_t)(b * NHEADS + h) * NSEQ + i0) * HD;
  const unsigned short* kb = kh + (size_t)(b * NHEADS + h) * NSEQ * HD;
  const unsigned short* vb = vt + (size_t)(b * NHEADS + h) * HD * NSEQ;

  // Q fragments (B-operand of swapped QK^T): lane holds Q[q=qg*16+lc][k=k0+lg*8+m]
  s16x8 aq[2][2];
#pragma unroll
  for (int qg = 0; qg < 2; qg++) {
    aq[qg][0] = *(const s16x8*)&qb[(qg * 16 + lc) * HD + lg * 8];
    aq[qg][1] = *(const s16x8*)&qb[(qg * 16 + lc) * HD + 32 + lg * 8];
  }

  // ---- QK^T (swapped) + exp, e -> registers ----
  float psum[2] = {0.f, 0.f};
  s16x4 ebf[2][8];                    // [qg][jt]: e(q=qg*16+lc, j=wcb+jt*16+lg*4+r)
  const unsigned short* krow = kb + (size_t)(wcb + lc) * HD + lg * 8;
  s16x8 kp[2][2];
  kp[0][0] = *(const s16x8*)&krow[0];
  kp[0][1] = *(const s16x8*)&krow[32];
#pragma unroll
  for (int jt = 0; jt < 8; jt++) {
    if (jt < 7) {
      kp[(jt + 1) & 1][0] = *(const s16x8*)&krow[(size_t)((jt + 1) * 16) * HD];
      kp[(jt + 1) & 1][1] = *(const s16x8*)&krow[(size_t)((jt + 1) * 16) * HD + 32];
    }
#pragma unroll
    for (int qg = 0; qg < 2; qg++) {
      f32x4 acc = {};
      acc = __builtin_amdgcn_mfma_f32_16x16x32_bf16(kp[jt & 1][0], aq[qg][0], acc, 0, 0, 0);
      acc = __builtin_amdgcn_mfma_f32_16x16x32_bf16(kp[jt & 1][1], aq[qg][1], acc, 0, 0, 0);
      float e0 = __expf(acc[0] * SCALEF);
      float e1 = __expf(acc[1] * SCALEF);
      float e2 = __expf(acc[2] * SCALEF);
      float e3 = __expf(acc[3] * SCALEF);
      psum[qg] += (e0 + e1) + (e2 + e3);
      s16x4 p;
      p[0] = (short)f2bf(e0); p[1] = (short)f2bf(e1);
      p[2] = (short)f2bf(e2); p[3] = (short)f2bf(e3);
      ebf[qg][jt] = p;
    }
  }
  // row-sum: lanes {lc, lc+16, lc+32, lc+48} hold disjoint j's of row lc
#pragma unroll
  for (int qg = 0; qg < 2; qg++) {
    psum[qg] += __shfl_xor(psum[qg], 16);
    psum[qg] += __shfl_xor(psum[qg], 32);
  }
  if (lg == 0) {
    wred[wid][lc] = psum[0];
    wred[wid][16 + lc] = psum[1];
  }
  __syncthreads();
  if (tid < 32) {
    float tot = 0.f;
#pragma unroll
    for (int w = 0; w < 16; w++) tot += wred[w][tid];
    invr[tid] = 1.0f / tot;
  }
  __syncthreads();
  const float inv0 = invr[lc];
  const float inv1 = invr[16 + lc];

  // ---- PV (K=16 mfma, B-frag direct from ebf) + interleaved attn stores ----
  f32x4 acc_o[4][2] = {};             // [dt][qg]: out^T[d=dt*16+lg*4+r][q=qg*16+lc]
  float* arow0 = attn_g + ((size_t)(b * NHEADS + h) * NSEQ + i0 + lc) * NSEQ + wcb + lg * 4;
  float* arow1 = arow0 + (size_t)16 * NSEQ;
#pragma unroll
  for (int jt = 0; jt < 8; jt++) {
    // A-frags: V^T[d=dt*16+lc][j=wcb+jt*16+lg*4+m]
    s16x4 vf[4];
#pragma unroll
    for (int dt = 0; dt < 4; dt++)
      vf[dt] = *(const s16x4*)&vb[(size_t)(dt * 16 + lc) * NSEQ + wcb + jt * 16 + lg * 4];
    // attn store for this j-tile (fire-and-forget, drains under MFMAs)
    {
      f32x4 s0, s1;
#pragma unroll
      for (int r = 0; r < 4; r++) {
        s0[r] = bf2f((unsigned short)ebf[0][jt][r]) * inv0;
        s1[r] = bf2f((unsigned short)ebf[1][jt][r]) * inv1;
      }
      *(f32x4*)&arow0[jt * 16] = s0;
      *(f32x4*)&arow1[jt * 16] = s1;
    }
#pragma unroll
    for (int dt = 0; dt < 4; dt++) {
#pragma unroll
      for (int qg = 0; qg < 2; qg++) {
        asm volatile("v_mfma_f32_16x16x16_bf16 %0, %1, %2, %0"
                     : "+v"(acc_o[dt][qg])
                     : "v"(vf[dt]), "v"(ebf[qg][jt]));
      }
    }
  }
  asm volatile("s_nop 7\n\ts_nop 7" ::: "memory");  // MFMA->VALU/LDS read guard

  // ---- staged cross-wave reduce: waves 0-7 write, 8-15 accumulate ----
  if (wid < 8) {
#pragma unroll
    for (int dt = 0; dt < 4; dt++)
#pragma unroll
      for (int qg = 0; qg < 2; qg++)
#pragma unroll
        for (int r = 0; r < 4; r++)
          part[wid][qg * 16 + lc][dt * 16 + lg * 4 + r] = acc_o[dt][qg][r];
  }
  __syncthreads();
  if (wid >= 8) {
#pragma unroll
    for (int dt = 0; dt < 4; dt++)
#pragma unroll
      for (int qg = 0; qg < 2; qg++)
#pragma unroll
        for (int r = 0; r < 4; r++)
          part[wid - 8][qg * 16 + lc][dt * 16 + lg * 4 + r] += acc_o[dt][qg][r];
  }
  __syncthreads();

  // ---- ctx reduce, normalize, bf16, write ctx [B][N][H*64] ----
  {
    const int oi = tid >> 5;          // 0..31
    const int d0 = (tid & 31) * 2;    // 0..62
    float s0 = 0.f, s1 = 0.f;
#pragma unroll
    for (int p = 0; p < 8; p++) {
      s0 += part[p][oi][d0];
      s1 += part[p][oi][d0 + 1];
    }
    float iv = invr[oi];
    ushort2 o;
    o.x = f2bf(s0 * iv);
    o.y = f2bf(s1 * iv);
    *(ushort2*)&ctx[(size_t)(b * NSEQ + i0 + oi) * DMODEL + h * HD + d0] = o;
  }
}

extern "C" void kernel_launch(void* const* d_in, const int* in_sizes, int n_in,
                              void* d_out, int out_size, void* d_ws, size_t ws_size,
                              hipStream_t stream) {
  const float* src     = (const float*)d_in[0];
  const float* sin_src = (const float*)d_in[1];
  const float* cos_src = (const float*)d_in[2];
  const float* tgt     = (const float*)d_in[3];
  const float* sin_tgt = (const float*)d_in[4];
  const float* cos_tgt = (const float*)d_in[5];
  const float* wq      = (const float*)d_in[6];
  const float* wkv     = (const float*)d_in[7];
  const float* wout    = (const float*)d_in[8];
  const float* bout    = (const float*)d_in[9];

  if (ws_size < (size_t)109051904) return;

  uint8_t* w = (uint8_t*)d_ws;
  unsigned short* tgt_bf = (unsigned short*)(w + 0);
  unsigned short* src_bf = (unsigned short*)(w + 8388608);
  unsigned short* wq_t   = (unsigned short*)(w + 16777216);
  unsigned short* wkv_t  = (unsigned short*)(w + 18874368);
  unsigned short* wout_t = (unsigned short*)(w + 23068672);
  float*          q_ws   = (float*)(w + 25165824);
  float*          kv_ws  = (float*)(w + 41943040);
  unsigned short* qhb    = (unsigned short*)(w + 75497472);
  unsigned short* khb    = (unsigned short*)(w + 83886080);
  unsigned short* vtb    = (unsigned short*)(w + 92274688);
  unsigned short* ctx    = (unsigned short*)(w + 100663296);

  float* out_p  = (float*)d_out;
  float* attn_p = out_p + (size_t)NB * NSEQ * DMODEL;

  k_convert<<<4096, 256, 0, stream>>>(tgt, tgt_bf, 1048576);
  k_convert<<<4096, 256, 0, stream>>>(src, src_bf, 1048576);
  k_transpose<<<dim3(16, 16), 256, 0, stream>>>(wq,   wq_t,   1024, 1024);
  k_transpose<<<dim3(32, 16), 256, 0, stream>>>(wkv,  wkv_t,  1024, 2048);
  k_transpose<<<dim3(16, 16), 256, 0, stream>>>(wout, wout_t, 1024, 1024);

  k_gemm<<<dim3(8, 32),  256, 0, stream>>>(tgt_bf, wq_t,  q_ws,  nullptr, 4096, 1024, 1024);
  k_gemm<<<dim3(16, 32), 256, 0, stream>>>(src_bf, wkv_t, kv_ws, nullptr, 4096, 2048, 1024);

  k_rope<<<8192, 256, 0, stream>>>(q_ws, 1024, sin_tgt, cos_tgt, qhb);
  k_rope<<<8192, 256, 0, stream>>>(kv_ws, 2048, sin_src, cos_src, khb);
  k_vtrans<<<dim3(32, 16, 2), 256, 0, stream>>>(kv_ws, vtb);

  k_attn<<<dim3(64, 16, 2), 1024, 0, stream>>>(qhb, khb, vtb, attn_p, ctx);

  k_gemm<<<dim3(8, 32), 256, 0, stream>>>(ctx, wout_t, out_p, bout, 4096, 1024, 1024);
}

// Round 10
// 452.224 us; speedup vs baseline: 1.0465x; 1.0465x over previous
//
#include <hip/hip_runtime.h>
#include <hip/hip_bf16.h>
#include <cstdint>
#include <cstddef>

#define NB 2
#define NSEQ 2048
#define NHEADS 16
#define HD 64
#define DMODEL 1024
#define SCALEF 0.125f

typedef __attribute__((ext_vector_type(4))) float f32x4;
typedef __attribute__((ext_vector_type(8))) short s16x8;
typedef __attribute__((ext_vector_type(4))) short s16x4;

__device__ __forceinline__ unsigned short f2bf(float f) {
  union { float f; unsigned u; } v; v.f = f;
  unsigned u = v.u;
  return (unsigned short)((u + 0x7fffu + ((u >> 16) & 1u)) >> 16);
}
__device__ __forceinline__ float bf2f(unsigned short s) {
  union { unsigned u; float f; } v; v.u = ((unsigned)s) << 16;
  return v.f;
}

// ---------- fp32 -> bf16 straight convert (float4 vectorized) ----------
__global__ void k_convert(const float* __restrict__ in, unsigned short* __restrict__ out, int n4) {
  int i = blockIdx.x * blockDim.x + threadIdx.x;
  if (i >= n4) return;
  float4 v = ((const float4*)in)[i];
  ushort4 o;
  o.x = f2bf(v.x); o.y = f2bf(v.y); o.z = f2bf(v.z); o.w = f2bf(v.w);
  ((ushort4*)out)[i] = o;
}

// ---------- w [K][N] fp32 -> wt [N][K] bf16 (LDS-tiled transpose) ----------
__global__ void k_transpose(const float* __restrict__ w, unsigned short* __restrict__ wt, int K, int N) {
  __shared__ float t[64][65];
  int n0 = blockIdx.x * 64, k0 = blockIdx.y * 64;
  int c = threadIdx.x & 63, rb = threadIdx.x >> 6;
#pragma unroll
  for (int rr = 0; rr < 16; rr++) {
    int k = rb * 16 + rr;
    t[c][k] = w[(size_t)(k0 + k) * N + n0 + c];
  }
  __syncthreads();
#pragma unroll
  for (int rr = 0; rr < 16; rr++) {
    int n = rb * 16 + rr;
    wt[(size_t)(n0 + n) * K + k0 + c] = f2bf(t[n][c]);
  }
}

// ---------- bf16 MFMA GEMM: C[M][N] = A[M][K] @ Bt[N][K]^T (+bias) ----------
#define GLD16(gp, lp) __builtin_amdgcn_global_load_lds( \
    (const __attribute__((address_space(1))) unsigned int*)(gp), \
    (__attribute__((address_space(3))) unsigned int*)(lp), 16, 0, 0)

__global__ __launch_bounds__(256) void k_gemm(const unsigned short* __restrict__ A,
                                              const unsigned short* __restrict__ Bt,
                                              float* __restrict__ C,
                                              const float* __restrict__ bias,
                                              int M, int N, int K) {
  __shared__ unsigned short As[128 * 32];
  __shared__ unsigned short Bs[128 * 32];
  const int tid = threadIdx.x;
  const int lane = tid & 63, wid = tid >> 6;
  const int m0 = blockIdx.y * 128, n0 = blockIdx.x * 128;
  const int wr = wid >> 1, wc = wid & 1;
  const int lr = lane >> 2, l4 = lane & 3;
  const int lc = lane & 15, lg = lane >> 4;

  const unsigned short* pa0 = A + (size_t)(m0 + wid * 32 + lr) * K + l4 * 8;
  const unsigned short* pa1 = pa0 + (size_t)16 * K;
  const unsigned short* pb0 = Bt + (size_t)(n0 + wid * 32 + lr) * K + l4 * 8;
  const unsigned short* pb1 = pb0 + (size_t)16 * K;

  f32x4 acc[4][4] = {};

  for (int kt = 0; kt < K; kt += 32) {
    GLD16(pa0 + kt, &As[wid * 1024]);
    GLD16(pa1 + kt, &As[wid * 1024 + 512]);
    GLD16(pb0 + kt, &Bs[wid * 1024]);
    GLD16(pb1 + kt, &Bs[wid * 1024 + 512]);
    __syncthreads();
    s16x8 af[4], bfr[4];
#pragma unroll
    for (int m = 0; m < 4; m++)
      af[m] = *(const s16x8*)&As[(wr * 64 + m * 16 + lc) * 32 + lg * 8];
#pragma unroll
    for (int n = 0; n < 4; n++)
      bfr[n] = *(const s16x8*)&Bs[(wc * 64 + n * 16 + lc) * 32 + lg * 8];
    __builtin_amdgcn_s_setprio(1);
#pragma unroll
    for (int m = 0; m < 4; m++)
#pragma unroll
      for (int n = 0; n < 4; n++)
        acc[m][n] = __builtin_amdgcn_mfma_f32_16x16x32_bf16(af[m], bfr[n], acc[m][n], 0, 0, 0);
    __builtin_amdgcn_s_setprio(0);
    __syncthreads();
  }

  float bv[4] = {0.f, 0.f, 0.f, 0.f};
  if (bias) {
#pragma unroll
    for (int n = 0; n < 4; n++) bv[n] = bias[n0 + wc * 64 + n * 16 + lc];
  }
#pragma unroll
  for (int m = 0; m < 4; m++) {
#pragma unroll
    for (int n = 0; n < 4; n++) {
      int col = n0 + wc * 64 + n * 16 + lc;
#pragma unroll
      for (int r = 0; r < 4; r++) {
        int row = m0 + wr * 64 + m * 16 + lg * 4 + r;
        C[(size_t)row * N + col] = acc[m][n][r] + bv[n];
      }
    }
  }
}

// ---------- RoPE + head-split relayout: [B][N][H*64] f32 -> [B][H][N][64] bf16 ----------
__global__ void k_rope(const float* __restrict__ src, int row_stride,
                       const float* __restrict__ sinp, const float* __restrict__ cosp,
                       unsigned short* __restrict__ dst) {
  int tid = blockIdx.x * 256 + threadIdx.x;
  int p = tid & 31;
  int h = (tid >> 5) & 15;
  int i = (tid >> 9) & 2047;
  int b = tid >> 20;
  int d = p * 2;
  float2 x = *(const float2*)(src + (size_t)(b * NSEQ + i) * row_stride + h * HD + d);
  float o0, o1;
  if (p < 16) {
    size_t sc = (size_t)(b * NSEQ + i) * 32 + d;
    float2 cc = *(const float2*)(cosp + sc);
    float2 ss = *(const float2*)(sinp + sc);
    o0 = x.x * cc.x - x.y * ss.x;
    o1 = x.y * cc.y + x.x * ss.y;
  } else { o0 = x.x; o1 = x.y; }
  size_t off = ((size_t)(b * NHEADS + h) * NSEQ + i) * HD + d;
  unsigned pack = (unsigned)f2bf(o0) | ((unsigned)f2bf(o1) << 16);
  *(unsigned*)(dst + off) = pack;
}

// ---------- v relayout+transpose: kv[B][N][2048](cols 1024..) -> vt [B][H][64][N] bf16 ----------
__global__ void k_vtrans(const float* __restrict__ kv, unsigned short* __restrict__ vt) {
  __shared__ float t[64][65];
  int i0 = blockIdx.x * 64;
  int h = blockIdx.y, b = blockIdx.z;
  int c = threadIdx.x & 63, rb = threadIdx.x >> 6;
#pragma unroll
  for (int rr = 0; rr < 16; rr++) {
    int il = rb * 16 + rr;
    t[il][c] = kv[(size_t)(b * NSEQ + i0 + il) * 2048 + 1024 + h * HD + c];
  }
  __syncthreads();
#pragma unroll
  for (int rr = 0; rr < 16; rr++) {
    int dd = rb * 16 + rr;
    vt[((size_t)(b * NHEADS + h) * HD + dd) * NSEQ + i0 + c] = f2bf(t[c][dd]);
  }
}

// ---------- fused attention v9: v8 + spill fix + part pad + V ring ----------
// r9 diagnosis: VGPR=64 (compiler targeted 8 waves/SIMD) forced spilling of
// the ~95-register live set -> scratch traffic. Fix: amdgpu_waves_per_eu(4,4)
// unlocks the 128-VGPR tier. part padded [32][65] kills the 16-way bank
// conflict (18.3M cy). V-fragments get a 2-deep ring. MFMA asm non-volatile
// so the scheduler can interleave loads/stores between them.
#define QBLK 32
__global__ __launch_bounds__(1024)
__attribute__((amdgpu_waves_per_eu(4, 4)))
void k_attn(const unsigned short* __restrict__ qh,
            const unsigned short* __restrict__ kh,
            const unsigned short* __restrict__ vt,
            float* __restrict__ attn_g,
            unsigned short* __restrict__ ctx) {
  __shared__ float part[8][32][65];   // 66,560 B (pad 65: conflict-free)
  __shared__ float wred[16][32];
  __shared__ float invr[32];

  const int tid = threadIdx.x;
  const int lane = tid & 63, wid = tid >> 6;     // wid 0..15
  const int i0 = blockIdx.x * QBLK;
  const int h = blockIdx.y, b = blockIdx.z;
  const int lc = lane & 15, lg = lane >> 4;
  const int wcb = wid * 128;                     // wave's 128-col j-slice

  const unsigned short* qb = qh + ((size_t)(b * NHEADS + h) * NSEQ + i0) * HD;
  const unsigned short* kb = kh + (size_t)(b * NHEADS + h) * NSEQ * HD;
  const unsigned short* vb = vt + (size_t)(b * NHEADS + h) * HD * NSEQ;

  // Q fragments (B-operand of swapped QK^T): lane holds Q[q=qg*16+lc][k=lg*8+m]
  s16x8 aq[2][2];
#pragma unroll
  for (int qg = 0; qg < 2; qg++) {
    aq[qg][0] = *(const s16x8*)&qb[(qg * 16 + lc) * HD + lg * 8];
    aq[qg][1] = *(const s16x8*)&qb[(qg * 16 + lc) * HD + 32 + lg * 8];
  }

  // ---- QK^T (swapped) + exp, e -> registers ----
  float psum[2] = {0.f, 0.f};
  s16x4 ebf[2][8];                    // [qg][jt]: e(q=qg*16+lc, j=wcb+jt*16+lg*4+r)
  const unsigned short* krow = kb + (size_t)(wcb + lc) * HD + lg * 8;
  s16x8 kp[2][2];
  kp[0][0] = *(const s16x8*)&krow[0];
  kp[0][1] = *(const s16x8*)&krow[32];
#pragma unroll
  for (int jt = 0; jt < 8; jt++) {
    if (jt < 7) {
      kp[(jt + 1) & 1][0] = *(const s16x8*)&krow[(size_t)((jt + 1) * 16) * HD];
      kp[(jt + 1) & 1][1] = *(const s16x8*)&krow[(size_t)((jt + 1) * 16) * HD + 32];
    }
#pragma unroll
    for (int qg = 0; qg < 2; qg++) {
      f32x4 acc = {};
      acc = __builtin_amdgcn_mfma_f32_16x16x32_bf16(kp[jt & 1][0], aq[qg][0], acc, 0, 0, 0);
      acc = __builtin_amdgcn_mfma_f32_16x16x32_bf16(kp[jt & 1][1], aq[qg][1], acc, 0, 0, 0);
      float e0 = __expf(acc[0] * SCALEF);
      float e1 = __expf(acc[1] * SCALEF);
      float e2 = __expf(acc[2] * SCALEF);
      float e3 = __expf(acc[3] * SCALEF);
      psum[qg] += (e0 + e1) + (e2 + e3);
      s16x4 p;
      p[0] = (short)f2bf(e0); p[1] = (short)f2bf(e1);
      p[2] = (short)f2bf(e2); p[3] = (short)f2bf(e3);
      ebf[qg][jt] = p;
    }
  }
  // row-sum: lanes {lc, lc+16, lc+32, lc+48} hold disjoint j's of row lc
#pragma unroll
  for (int qg = 0; qg < 2; qg++) {
    psum[qg] += __shfl_xor(psum[qg], 16);
    psum[qg] += __shfl_xor(psum[qg], 32);
  }
  if (lg == 0) {
    wred[wid][lc] = psum[0];
    wred[wid][16 + lc] = psum[1];
  }
  __syncthreads();
  if (tid < 32) {
    float tot = 0.f;
#pragma unroll
    for (int w = 0; w < 16; w++) tot += wred[w][tid];
    invr[tid] = 1.0f / tot;
  }
  __syncthreads();
  const float inv0 = invr[lc];
  const float inv1 = invr[16 + lc];

  // ---- PV (K=16 mfma, B-frag direct from ebf) + interleaved attn stores ----
  f32x4 acc_o[4][2] = {};             // [dt][qg]: out^T[d=dt*16+lg*4+r][q=qg*16+lc]
  float* arow0 = attn_g + ((size_t)(b * NHEADS + h) * NSEQ + i0 + lc) * NSEQ + wcb + lg * 4;
  float* arow1 = arow0 + (size_t)16 * NSEQ;
  const unsigned short* vrow = vb + (size_t)lc * NSEQ + wcb + lg * 4;
  s16x4 vf[2][4];
#pragma unroll
  for (int dt = 0; dt < 4; dt++)
    vf[0][dt] = *(const s16x4*)&vrow[(size_t)(dt * 16) * NSEQ];
#pragma unroll
  for (int jt = 0; jt < 8; jt++) {
    if (jt < 7) {
#pragma unroll
      for (int dt = 0; dt < 4; dt++)
        vf[(jt + 1) & 1][dt] = *(const s16x4*)&vrow[(size_t)(dt * 16) * NSEQ + (jt + 1) * 16];
    }
    // attn store for this j-tile (drains under MFMAs)
    {
      f32x4 s0, s1;
#pragma unroll
      for (int r = 0; r < 4; r++) {
        s0[r] = bf2f((unsigned short)ebf[0][jt][r]) * inv0;
        s1[r] = bf2f((unsigned short)ebf[1][jt][r]) * inv1;
      }
      *(f32x4*)&arow0[jt * 16] = s0;
      *(f32x4*)&arow1[jt * 16] = s1;
    }
#pragma unroll
    for (int dt = 0; dt < 4; dt++) {
#pragma unroll
      for (int qg = 0; qg < 2; qg++) {
        asm("v_mfma_f32_16x16x16_bf16 %0, %1, %2, %0"
            : "+v"(acc_o[dt][qg])
            : "v"(vf[jt & 1][dt]), "v"(ebf[qg][jt]));
      }
    }
  }
  asm volatile("s_nop 7\n\ts_nop 7" ::: "memory");  // MFMA->read guard

  // ---- staged cross-wave reduce: waves 0-7 write, 8-15 accumulate ----
  if (wid < 8) {
#pragma unroll
    for (int dt = 0; dt < 4; dt++)
#pragma unroll
      for (int qg = 0; qg < 2; qg++)
#pragma unroll
        for (int r = 0; r < 4; r++)
          part[wid][qg * 16 + lc][dt * 16 + lg * 4 + r] = acc_o[dt][qg][r];
  }
  __syncthreads();
  if (wid >= 8) {
#pragma unroll
    for (int dt = 0; dt < 4; dt++)
#pragma unroll
      for (int qg = 0; qg < 2; qg++)
#pragma unroll
        for (int r = 0; r < 4; r++)
          part[wid - 8][qg * 16 + lc][dt * 16 + lg * 4 + r] += acc_o[dt][qg][r];
  }
  __syncthreads();

  // ---- ctx reduce, normalize, bf16, write ctx [B][N][H*64] ----
  {
    const int oi = tid >> 5;          // 0..31
    const int d0 = (tid & 31) * 2;    // 0..62
    float s0 = 0.f, s1 = 0.f;
#pragma unroll
    for (int p = 0; p < 8; p++) {
      s0 += part[p][oi][d0];
      s1 += part[p][oi][d0 + 1];
    }
    float iv = invr[oi];
    ushort2 o;
    o.x = f2bf(s0 * iv);
    o.y = f2bf(s1 * iv);
    *(ushort2*)&ctx[(size_t)(b * NSEQ + i0 + oi) * DMODEL + h * HD + d0] = o;
  }
}

extern "C" void kernel_launch(void* const* d_in, const int* in_sizes, int n_in,
                              void* d_out, int out_size, void* d_ws, size_t ws_size,
                              hipStream_t stream) {
  const float* src     = (const float*)d_in[0];
  const float* sin_src = (const float*)d_in[1];
  const float* cos_src = (const float*)d_in[2];
  const float* tgt     = (const float*)d_in[3];
  const float* sin_tgt = (const float*)d_in[4];
  const float* cos_tgt = (const float*)d_in[5];
  const float* wq      = (const float*)d_in[6];
  const float* wkv     = (const float*)d_in[7];
  const float* wout    = (const float*)d_in[8];
  const float* bout    = (const float*)d_in[9];

  if (ws_size < (size_t)109051904) return;

  uint8_t* w = (uint8_t*)d_ws;
  unsigned short* tgt_bf = (unsigned short*)(w + 0);
  unsigned short* src_bf = (unsigned short*)(w + 8388608);
  unsigned short* wq_t   = (unsigned short*)(w + 16777216);
  unsigned short* wkv_t  = (unsigned short*)(w + 18874368);
  unsigned short* wout_t = (unsigned short*)(w + 23068672);
  float*          q_ws   = (float*)(w + 25165824);
  float*          kv_ws  = (float*)(w + 41943040);
  unsigned short* qhb    = (unsigned short*)(w + 75497472);
  unsigned short* khb    = (unsigned short*)(w + 83886080);
  unsigned short* vtb    = (unsigned short*)(w + 92274688);
  unsigned short* ctx    = (unsigned short*)(w + 100663296);

  float* out_p  = (float*)d_out;
  float* attn_p = out_p + (size_t)NB * NSEQ * DMODEL;

  k_convert<<<4096, 256, 0, stream>>>(tgt, tgt_bf, 1048576);
  k_convert<<<4096, 256, 0, stream>>>(src, src_bf, 1048576);
  k_transpose<<<dim3(16, 16), 256, 0, stream>>>(wq,   wq_t,   1024, 1024);
  k_transpose<<<dim3(32, 16), 256, 0, stream>>>(wkv,  wkv_t,  1024, 2048);
  k_transpose<<<dim3(16, 16), 256, 0, stream>>>(wout, wout_t, 1024, 1024);

  k_gemm<<<dim3(8, 32),  256, 0, stream>>>(tgt_bf, wq_t,  q_ws,  nullptr, 4096, 1024, 1024);
  k_gemm<<<dim3(16, 32), 256, 0, stream>>>(src_bf, wkv_t, kv_ws, nullptr, 4096, 2048, 1024);

  k_rope<<<8192, 256, 0, stream>>>(q_ws, 1024, sin_tgt, cos_tgt, qhb);
  k_rope<<<8192, 256, 0, stream>>>(kv_ws, 2048, sin_src, cos_src, khb);
  k_vtrans<<<dim3(32, 16, 2), 256, 0, stream>>>(kv_ws, vtb);

  k_attn<<<dim3(64, 16, 2), 1024, 0, stream>>>(qhb, khb, vtb, attn_p, ctx);

  k_gemm<<<dim3(8, 32), 256, 0, stream>>>(ctx, wout_t, out_p, bout, 4096, 1024, 1024);
}